// Round 4
// baseline (267.819 us; speedup 1.0000x reference)
//
#include <hip/hip_runtime.h>
#include <math.h>

#define SEQ    4096
#define DMODEL 1024
#define NHEAD  16
#define DHEAD  64

typedef __bf16 bf16;
typedef bf16  bf16x2 __attribute__((ext_vector_type(2)));
typedef bf16  bf16x8 __attribute__((ext_vector_type(8)));
typedef float f32x4  __attribute__((ext_vector_type(4)));

// involutive 16B-chunk swizzle
#define SWZ(r) ((((r) >> 2) ^ (r)) & 7)

__device__ __forceinline__ void gll16(const void* g, void* l) {
    __builtin_amdgcn_global_load_lds(
        (const __attribute__((address_space(1))) void*)g,
        (__attribute__((address_space(3))) void*)l, 16, 0, 0);
}

// ---------------------------------------------------------------------------
// fp32 -> bf16 convert (memory-bound, vectorized)
// ---------------------------------------------------------------------------
__global__ __launch_bounds__(256)
void cvt_bf16(const float* __restrict__ s, bf16* __restrict__ d, int n)
{
    const int i = (blockIdx.x * 256 + threadIdx.x) * 8;
    if (i >= n) return;
    float4 a = *(const float4*)&s[i];
    float4 b = *(const float4*)&s[i + 4];
    bf16x8 v;
    v[0] = (bf16)a.x; v[1] = (bf16)a.y; v[2] = (bf16)a.z; v[3] = (bf16)a.w;
    v[4] = (bf16)b.x; v[5] = (bf16)b.y; v[6] = (bf16)b.z; v[7] = (bf16)b.w;
    *(bf16x8*)&d[i] = v;
}

// ---------------------------------------------------------------------------
// bf16 MFMA GEMM:  C[M][N] = A[M][K] * B[N][K]^T   (unchanged from R3)
// ---------------------------------------------------------------------------
template<int EPI>
__global__ __launch_bounds__(256)
void gemm_mfma(const bf16* __restrict__ A, const bf16* __restrict__ B,
               bf16* __restrict__ Cb, float* __restrict__ Cf,
               const float* __restrict__ res, int M, int N, int K)
{
    const int bm   = blockIdx.y * 64;
    const int bn   = blockIdx.x * 128;
    const int tid  = threadIdx.x;
    const int w    = tid >> 6;
    const int lane = tid & 63;
    const int lr   = lane & 15;
    const int lh   = lane >> 4;
    const int wr   = w >> 1;
    const int wc   = w & 1;
    const int lrow = lane >> 3;
    const int lch  = lane & 7;

    __shared__ bf16 As[64 * 64];
    __shared__ bf16 Bs[128 * 64];

    f32x4 acc[2][4] = {};

    for (int k0 = 0; k0 < K; k0 += 64) {
        __syncthreads();
        #pragma unroll
        for (int i = 0; i < 2; ++i) {
            const int r = (w * 2 + i) * 8 + lrow;
            gll16(A + (size_t)(bm + r) * K + k0 + ((lch ^ SWZ(r)) << 3),
                  &As[(w * 2 + i) * 512]);
        }
        #pragma unroll
        for (int i = 0; i < 4; ++i) {
            const int r = (w * 4 + i) * 8 + lrow;
            gll16(B + (size_t)(bn + r) * K + k0 + ((lch ^ SWZ(r)) << 3),
                  &Bs[(w * 4 + i) * 512]);
        }
        asm volatile("s_waitcnt vmcnt(0)" ::: "memory");
        __syncthreads();

        bf16x8 af[2][2], bfr[4][2];
        #pragma unroll
        for (int rt = 0; rt < 2; ++rt)
            #pragma unroll
            for (int s = 0; s < 2; ++s) {
                const int r = wr * 32 + rt * 16 + lr;
                af[rt][s] = *(const bf16x8*)&As[r * 64 + (((s * 4 + lh) ^ SWZ(r)) << 3)];
            }
        #pragma unroll
        for (int ct = 0; ct < 4; ++ct)
            #pragma unroll
            for (int s = 0; s < 2; ++s) {
                const int r = wc * 64 + ct * 16 + lr;
                bfr[ct][s] = *(const bf16x8*)&Bs[r * 64 + (((s * 4 + lh) ^ SWZ(r)) << 3)];
            }
        __builtin_amdgcn_s_setprio(1);
        #pragma unroll
        for (int rt = 0; rt < 2; ++rt)
            #pragma unroll
            for (int ct = 0; ct < 4; ++ct)
                #pragma unroll
                for (int s = 0; s < 2; ++s)
                    acc[rt][ct] = __builtin_amdgcn_mfma_f32_16x16x32_bf16(
                        af[rt][s], bfr[ct][s], acc[rt][ct], 0, 0, 0);
        __builtin_amdgcn_s_setprio(0);
    }

    #pragma unroll
    for (int rt = 0; rt < 2; ++rt)
        #pragma unroll
        for (int ct = 0; ct < 4; ++ct)
            #pragma unroll
            for (int r = 0; r < 4; ++r) {
                const int m = bm + wr * 32 + rt * 16 + lh * 4 + r;
                const int n = bn + wc * 64 + ct * 16 + lr;
                if (EPI == 0) {
                    Cb[(size_t)m * N + n] = (bf16)acc[rt][ct][r];
                } else {
                    Cf[(size_t)m * N + n] =
                        fmaxf(acc[rt][ct][r], 0.f) + res[(size_t)m * N + n];
                }
            }
}

// ---------------------------------------------------------------------------
// MFMA flash attention, double-buffered K/V, one barrier per chunk.
// Block = 4 waves x 32 q-rows = 128 q-rows of one head; KV chunk 64.
// ---------------------------------------------------------------------------
__global__ __launch_bounds__(256)
void attn_mfma(const bf16* __restrict__ Q, const bf16* __restrict__ K,
               const bf16* __restrict__ V, bf16* __restrict__ O)
{
    // XCD-aware swizzle: 512 blocks, 8 XCDs, 64 logical blocks (=2 heads) per XCD
    const int wg   = blockIdx.x;
    const int swz  = (wg & 7) * 64 + (wg >> 3);
    const int h    = swz >> 5;
    const int q0   = (swz & 31) * 128;

    const int tid  = threadIdx.x;
    const int w    = tid >> 6;
    const int lane = tid & 63;
    const int lr   = lane & 15;
    const int lh   = lane >> 4;
    const int lrow = lane >> 3;
    const int lch  = lane & 7;

    __shared__ bf16 Ks[2][64 * 64];     // 16 KB
    __shared__ bf16 Vt[2][64 * 64];     // 16 KB
    __shared__ bf16 Ps[4][32 * 64];     // 16 KB per-wave P
    bf16* Pw = Ps[w];

    // hoist Q fragments
    bf16x8 qf[2][2];
    #pragma unroll
    for (int rt = 0; rt < 2; ++rt)
        #pragma unroll
        for (int s = 0; s < 2; ++s)
            qf[rt][s] = *(const bf16x8*)&Q[(size_t)(q0 + w * 32 + rt * 16 + lr) * DMODEL
                                           + h * 64 + s * 32 + lh * 8];

    f32x4 acc[2][4] = {};
    float lsum[2][4] = {};

    const int vk = (tid & 7) * 8;       // key base for V transpose
    const int vd = (tid >> 3) * 2;      // d base (0..62)

    bf16x2 u[8];

    // ---- prologue: stage chunk 0 into buffer 0
    #pragma unroll
    for (int i = 0; i < 2; ++i) {
        const int r = (w * 2 + i) * 8 + lrow;
        gll16(K + (size_t)r * DMODEL + h * 64 + ((lch ^ SWZ(r)) << 3),
              &Ks[0][(w * 2 + i) * 512]);
    }
    #pragma unroll
    for (int i = 0; i < 8; ++i)
        u[i] = *(const bf16x2*)&V[(size_t)(vk + i) * DMODEL + h * 64 + vd];
    asm volatile("s_waitcnt vmcnt(0)" ::: "memory");
    {
        bf16x8 v0, v1;
        #pragma unroll
        for (int i = 0; i < 8; ++i) { v0[i] = u[i][0]; v1[i] = u[i][1]; }
        *(bf16x8*)&Vt[0][(vd + 0) * 64 + (((tid & 7) ^ SWZ(vd + 0)) << 3)] = v0;
        *(bf16x8*)&Vt[0][(vd + 1) * 64 + (((tid & 7) ^ SWZ(vd + 1)) << 3)] = v1;
    }
    __syncthreads();

    int cur = 0;
    for (int c = 0; c < SEQ; c += 64) {
        const int cn = (c + 64) & (SEQ - 1);   // wraps on last iter (harmless re-stage)

        // ---- issue next chunk's loads (hidden under compute)
        #pragma unroll
        for (int i = 0; i < 2; ++i) {
            const int r = (w * 2 + i) * 8 + lrow;
            gll16(K + (size_t)(cn + r) * DMODEL + h * 64 + ((lch ^ SWZ(r)) << 3),
                  &Ks[cur ^ 1][(w * 2 + i) * 512]);
        }
        #pragma unroll
        for (int i = 0; i < 8; ++i)
            u[i] = *(const bf16x2*)&V[(size_t)(cn + vk + i) * DMODEL + h * 64 + vd];

        // ---- QK^T: S[32 x 64] per wave
        const bf16* Kc = Ks[cur];
        f32x4 st[2][4] = {};
        __builtin_amdgcn_s_setprio(1);
        #pragma unroll
        for (int s = 0; s < 2; ++s)
            #pragma unroll
            for (int t = 0; t < 4; ++t) {
                const int r = t * 16 + lr;
                bf16x8 kf = *(const bf16x8*)&Kc[r * 64 + (((s * 4 + lh) ^ SWZ(r)) << 3)];
                st[0][t] = __builtin_amdgcn_mfma_f32_16x16x32_bf16(qf[0][s], kf, st[0][t], 0, 0, 0);
                st[1][t] = __builtin_amdgcn_mfma_f32_16x16x32_bf16(qf[1][s], kf, st[1][t], 0, 0, 0);
            }
        __builtin_amdgcn_s_setprio(0);

        // ---- softmax numerator (exp2 with folded scale) + P scatter
        #pragma unroll
        for (int rt = 0; rt < 2; ++rt)
            #pragma unroll
            for (int r4 = 0; r4 < 4; ++r4) {
                const int row = rt * 16 + lh * 4 + r4;
                float psum = 0.f;
                #pragma unroll
                for (int t = 0; t < 4; ++t) {
                    float sc = st[rt][t][r4] * 0.18033688f;   // 0.125 * log2(e)
                    sc = fminf(sc, 57.7f);
                    const float p = exp2f(sc);
                    psum += p;
                    const int col = t * 16 + lr;
                    Pw[row * 64 + ((((col >> 3) ^ SWZ(row)) << 3) | (col & 7))] = (bf16)p;
                }
                lsum[rt][r4] += psum;
            }

        // ---- PV: O[32 x 64] += P * V
        const bf16* Vc = Vt[cur];
        __builtin_amdgcn_s_setprio(1);
        #pragma unroll
        for (int s = 0; s < 2; ++s) {
            const int r0 = lr, r1 = 16 + lr;
            bf16x8 pf0 = *(const bf16x8*)&Pw[r0 * 64 + (((s * 4 + lh) ^ SWZ(r0)) << 3)];
            bf16x8 pf1 = *(const bf16x8*)&Pw[r1 * 64 + (((s * 4 + lh) ^ SWZ(r1)) << 3)];
            #pragma unroll
            for (int dt = 0; dt < 4; ++dt) {
                const int rd = dt * 16 + lr;
                bf16x8 vf = *(const bf16x8*)&Vc[rd * 64 + (((s * 4 + lh) ^ SWZ(rd)) << 3)];
                acc[0][dt] = __builtin_amdgcn_mfma_f32_16x16x32_bf16(pf0, vf, acc[0][dt], 0, 0, 0);
                acc[1][dt] = __builtin_amdgcn_mfma_f32_16x16x32_bf16(pf1, vf, acc[1][dt], 0, 0, 0);
            }
        }
        __builtin_amdgcn_s_setprio(0);

        // ---- drain next-chunk loads, write V transpose, single barrier
        asm volatile("s_waitcnt vmcnt(0)" ::: "memory");
        {
            bf16x8 v0, v1;
            #pragma unroll
            for (int i = 0; i < 8; ++i) { v0[i] = u[i][0]; v1[i] = u[i][1]; }
            bf16* Vn = Vt[cur ^ 1];
            *(bf16x8*)&Vn[(vd + 0) * 64 + (((tid & 7) ^ SWZ(vd + 0)) << 3)] = v0;
            *(bf16x8*)&Vn[(vd + 1) * 64 + (((tid & 7) ^ SWZ(vd + 1)) << 3)] = v1;
        }
        __syncthreads();
        cur ^= 1;
    }

    #pragma unroll
    for (int rt = 0; rt < 2; ++rt)
        #pragma unroll
        for (int r = 0; r < 4; ++r) {
            float s = lsum[rt][r];
            s += __shfl_xor(s, 1); s += __shfl_xor(s, 2);
            s += __shfl_xor(s, 4); s += __shfl_xor(s, 8);
            lsum[rt][r] = 1.0f / s;
        }

    #pragma unroll
    for (int rt = 0; rt < 2; ++rt)
        #pragma unroll
        for (int dt = 0; dt < 4; ++dt)
            #pragma unroll
            for (int r = 0; r < 4; ++r)
                O[(size_t)(q0 + w * 32 + rt * 16 + lh * 4 + r) * DMODEL
                  + h * 64 + dt * 16 + lr] = (bf16)(acc[rt][dt][r] * lsum[rt][r]);
}

// ---------------------------------------------------------------------------
extern "C" void kernel_launch(void* const* d_in, const int* in_sizes, int n_in,
                              void* d_out, int out_size, void* d_ws, size_t ws_size,
                              hipStream_t stream)
{
    const float* q   = (const float*)d_in[0];
    const float* k   = (const float*)d_in[1];
    const float* v   = (const float*)d_in[2];
    const float* Wq  = (const float*)d_in[3];
    const float* Wk  = (const float*)d_in[4];
    const float* Wv  = (const float*)d_in[5];
    const float* Wfc = (const float*)d_in[6];
    float* out = (float*)d_out;

    const int EM = SEQ * DMODEL;
    const int WM = DMODEL * DMODEL;

    bf16* qb   = (bf16*)d_ws;
    bf16* kb   = qb + EM;
    bf16* vb   = kb + EM;
    bf16* Wqb  = vb + EM;
    bf16* Wkb  = Wqb + WM;
    bf16* Wvb  = Wkb + WM;
    bf16* Wfcb = Wvb + WM;
    bf16* Pq   = Wfcb + WM;
    bf16* Pk   = Pq + EM;
    bf16* Pv   = Pk + EM;
    bf16* AO   = Pv + EM;

    cvt_bf16<<<EM / 2048, 256, 0, stream>>>(q,   qb,   EM);
    cvt_bf16<<<EM / 2048, 256, 0, stream>>>(k,   kb,   EM);
    cvt_bf16<<<EM / 2048, 256, 0, stream>>>(v,   vb,   EM);
    cvt_bf16<<<WM / 2048, 256, 0, stream>>>(Wq,  Wqb,  WM);
    cvt_bf16<<<WM / 2048, 256, 0, stream>>>(Wk,  Wkb,  WM);
    cvt_bf16<<<WM / 2048, 256, 0, stream>>>(Wv,  Wvb,  WM);
    cvt_bf16<<<WM / 2048, 256, 0, stream>>>(Wfc, Wfcb, WM);

    dim3 gg(DMODEL / 128, SEQ / 64);
    gemm_mfma<0><<<gg, 256, 0, stream>>>(qb, Wqb, Pq, nullptr, nullptr, SEQ, DMODEL, DMODEL);
    gemm_mfma<0><<<gg, 256, 0, stream>>>(kb, Wkb, Pk, nullptr, nullptr, SEQ, DMODEL, DMODEL);
    gemm_mfma<0><<<gg, 256, 0, stream>>>(vb, Wvb, Pv, nullptr, nullptr, SEQ, DMODEL, DMODEL);

    attn_mfma<<<512, 256, 0, stream>>>(Pq, Pk, Pv, AO);

    gemm_mfma<1><<<gg, 256, 0, stream>>>(AO, Wfcb, nullptr, out, q, SEQ, DMODEL, DMODEL);
}

// Round 5
// 219.386 us; speedup vs baseline: 1.2208x; 1.2208x over previous
//
#include <hip/hip_runtime.h>
#include <math.h>

#define SEQ    4096
#define DMODEL 1024
#define NHEAD  16
#define DHEAD  64

typedef __bf16 bf16;
typedef bf16  bf16x2 __attribute__((ext_vector_type(2)));
typedef bf16  bf16x4 __attribute__((ext_vector_type(4)));
typedef bf16  bf16x8 __attribute__((ext_vector_type(8)));
typedef float f32x4  __attribute__((ext_vector_type(4)));
typedef float f32x16 __attribute__((ext_vector_type(16)));
typedef unsigned int u32;

// involutive 16B-chunk swizzles
#define SWZ(r)  ((((r) >> 2) ^ (r)) & 7)                    // GEMM (unchanged)
#define SWZ3(r) (((r) ^ ((r) >> 2) ^ ((r) >> 3)) & 7)       // attn (distinct at d8/d16/d24)

__device__ __forceinline__ void gll16(const void* g, void* l) {
    __builtin_amdgcn_global_load_lds(
        (const __attribute__((address_space(1))) void*)g,
        (__attribute__((address_space(3))) void*)l, 16, 0, 0);
}

__device__ __forceinline__ u32 cvtpk(float lo, float hi) {
    u32 r;
    asm("v_cvt_pk_bf16_f32 %0, %1, %2" : "=v"(r) : "v"(lo), "v"(hi));
    return r;
}
__device__ __forceinline__ void pswap(u32& a, u32& b) {
    asm volatile("v_permlane32_swap_b32 %0, %1" : "+v"(a), "+v"(b));
}

// ---------------------------------------------------------------------------
// fp32 -> bf16 convert
// ---------------------------------------------------------------------------
__global__ __launch_bounds__(256)
void cvt_bf16(const float* __restrict__ s, bf16* __restrict__ d, int n)
{
    const int i = (blockIdx.x * 256 + threadIdx.x) * 8;
    if (i >= n) return;
    float4 a = *(const float4*)&s[i];
    float4 b = *(const float4*)&s[i + 4];
    bf16x8 v;
    v[0] = (bf16)a.x; v[1] = (bf16)a.y; v[2] = (bf16)a.z; v[3] = (bf16)a.w;
    v[4] = (bf16)b.x; v[5] = (bf16)b.y; v[6] = (bf16)b.z; v[7] = (bf16)b.w;
    *(bf16x8*)&d[i] = v;
}

// ---------------------------------------------------------------------------
// bf16 MFMA GEMM:  C[M][N] = A[M][K] * B[N][K]^T   (unchanged from R3/R4)
// ---------------------------------------------------------------------------
template<int EPI>
__global__ __launch_bounds__(256)
void gemm_mfma(const bf16* __restrict__ A, const bf16* __restrict__ B,
               bf16* __restrict__ Cb, float* __restrict__ Cf,
               const float* __restrict__ res, int M, int N, int K)
{
    const int bm   = blockIdx.y * 64;
    const int bn   = blockIdx.x * 128;
    const int tid  = threadIdx.x;
    const int w    = tid >> 6;
    const int lane = tid & 63;
    const int lr   = lane & 15;
    const int lh   = lane >> 4;
    const int wr   = w >> 1;
    const int wc   = w & 1;
    const int lrow = lane >> 3;
    const int lch  = lane & 7;

    __shared__ bf16 As[64 * 64];
    __shared__ bf16 Bs[128 * 64];

    f32x4 acc[2][4] = {};

    for (int k0 = 0; k0 < K; k0 += 64) {
        __syncthreads();
        #pragma unroll
        for (int i = 0; i < 2; ++i) {
            const int r = (w * 2 + i) * 8 + lrow;
            gll16(A + (size_t)(bm + r) * K + k0 + ((lch ^ SWZ(r)) << 3),
                  &As[(w * 2 + i) * 512]);
        }
        #pragma unroll
        for (int i = 0; i < 4; ++i) {
            const int r = (w * 4 + i) * 8 + lrow;
            gll16(B + (size_t)(bn + r) * K + k0 + ((lch ^ SWZ(r)) << 3),
                  &Bs[(w * 4 + i) * 512]);
        }
        asm volatile("s_waitcnt vmcnt(0)" ::: "memory");
        __syncthreads();

        bf16x8 af[2][2], bfr[4][2];
        #pragma unroll
        for (int rt = 0; rt < 2; ++rt)
            #pragma unroll
            for (int s = 0; s < 2; ++s) {
                const int r = wr * 32 + rt * 16 + lr;
                af[rt][s] = *(const bf16x8*)&As[r * 64 + (((s * 4 + lh) ^ SWZ(r)) << 3)];
            }
        #pragma unroll
        for (int ct = 0; ct < 4; ++ct)
            #pragma unroll
            for (int s = 0; s < 2; ++s) {
                const int r = wc * 64 + ct * 16 + lr;
                bfr[ct][s] = *(const bf16x8*)&Bs[r * 64 + (((s * 4 + lh) ^ SWZ(r)) << 3)];
            }
        __builtin_amdgcn_s_setprio(1);
        #pragma unroll
        for (int rt = 0; rt < 2; ++rt)
            #pragma unroll
            for (int ct = 0; ct < 4; ++ct)
                #pragma unroll
                for (int s = 0; s < 2; ++s)
                    acc[rt][ct] = __builtin_amdgcn_mfma_f32_16x16x32_bf16(
                        af[rt][s], bfr[ct][s], acc[rt][ct], 0, 0, 0);
        __builtin_amdgcn_s_setprio(0);
    }

    #pragma unroll
    for (int rt = 0; rt < 2; ++rt)
        #pragma unroll
        for (int ct = 0; ct < 4; ++ct)
            #pragma unroll
            for (int r = 0; r < 4; ++r) {
                const int m = bm + wr * 32 + rt * 16 + lh * 4 + r;
                const int n = bn + wc * 64 + ct * 16 + lr;
                if (EPI == 0) {
                    Cb[(size_t)m * N + n] = (bf16)acc[rt][ct][r];
                } else {
                    Cf[(size_t)m * N + n] =
                        fmaxf(acc[rt][ct][r], 0.f) + res[(size_t)m * N + n];
                }
            }
}

// ---------------------------------------------------------------------------
// MFMA flash attention, swapped-QK^T (32x32x16), in-register softmax.
// Block = 4 waves x 32 q-rows = 128 q-rows of one head; KV chunk 64, dbuf.
// mfma_f32_32x32x16_bf16 layouts:
//   A-frag: lane l supplies A[l&31][(l>>5)*8 + j]
//   B-frag: lane l supplies B[(l>>5)*8 + j][l&31]
//   C/D:    lane l reg r = D[(r&3) + 8*(r>>2) + 4*(l>>5)][l&31]
// QK^T: st = mfma(K, Q) = S^T[key][q]  -> lane owns q = lane&31, 32 keys in regs
// PV:   acc = mfma(V^T, P^T) = O^T[d][q]
// ---------------------------------------------------------------------------
__global__ __launch_bounds__(256)
void attn_mfma(const bf16* __restrict__ Q, const bf16* __restrict__ K,
               const bf16* __restrict__ V, bf16* __restrict__ O)
{
    const int wg   = blockIdx.x;
    const int swz  = (wg & 7) * 64 + (wg >> 3);
    const int h    = swz >> 5;
    const int q0   = (swz & 31) * 128;

    const int tid  = threadIdx.x;
    const int w    = tid >> 6;
    const int lane = tid & 63;
    const int lo5  = lane & 31;
    const int hi   = lane >> 5;
    const int lrow = lane >> 3;
    const int lch  = lane & 7;

    __shared__ bf16 Ks[2][64 * 64];     // 16 KB [key][d]
    __shared__ bf16 Vt[2][64 * 64];     // 16 KB [d][key]

    // Q fragments: lane owns q-row q0 + w*32 + lo5; slice s covers d = s*16+hi*8..+7
    const bf16* qrow = Q + (size_t)(q0 + w * 32 + lo5) * DMODEL + h * 64;
    bf16x8 qf[4];
    #pragma unroll
    for (int s = 0; s < 4; ++s)
        qf[s] = *(const bf16x8*)&qrow[s * 16 + hi * 8];

    f32x16 acc0 = {}, acc1 = {};        // O^T d-tiles 0-31, 32-63
    float ls0 = 0.f, ls1 = 0.f;

    const int vk = (tid & 7) * 8;       // key base for V transpose
    const int vd = (tid >> 3) * 2;      // d base

    const float SC = 0.18033688f;       // 0.125 * log2(e)

    // ---- prologue: stage chunk 0 into buffer 0
    #pragma unroll
    for (int i = 0; i < 2; ++i) {
        const int r = (w * 2 + i) * 8 + lrow;
        gll16(K + (size_t)r * DMODEL + h * 64 + ((lch ^ SWZ3(r)) << 3),
              &Ks[0][(w * 2 + i) * 512]);
    }
    {
        bf16x2 u[8];
        #pragma unroll
        for (int i = 0; i < 8; ++i)
            u[i] = *(const bf16x2*)&V[(size_t)(vk + i) * DMODEL + h * 64 + vd];
        asm volatile("s_waitcnt vmcnt(0)" ::: "memory");
        bf16x8 v0, v1;
        #pragma unroll
        for (int i = 0; i < 8; ++i) { v0[i] = u[i][0]; v1[i] = u[i][1]; }
        *(bf16x8*)&Vt[0][(vd + 0) * 64 + (((tid & 7) ^ SWZ3(vd + 0)) << 3)] = v0;
        *(bf16x8*)&Vt[0][(vd + 1) * 64 + (((tid & 7) ^ SWZ3(vd + 1)) << 3)] = v1;
    }
    __syncthreads();

#define BODY(CUR, CN)                                                          \
    {                                                                          \
        const int cn = (CN) & (SEQ - 1);                                       \
        /* issue next chunk K -> LDS[!CUR], V -> regs */                       \
        _Pragma("unroll")                                                      \
        for (int i = 0; i < 2; ++i) {                                          \
            const int r = (w * 2 + i) * 8 + lrow;                              \
            gll16(K + (size_t)(cn + r) * DMODEL + h * 64 + ((lch ^ SWZ3(r)) << 3), \
                  &Ks[(CUR) ^ 1][(w * 2 + i) * 512]);                          \
        }                                                                      \
        bf16x2 u[8];                                                           \
        _Pragma("unroll")                                                      \
        for (int i = 0; i < 8; ++i)                                            \
            u[i] = *(const bf16x2*)&V[(size_t)(cn + vk + i) * DMODEL + h * 64 + vd]; \
        /* QK^T swapped: S^T[key][q] */                                        \
        const bf16* Kc = Ks[CUR];                                              \
        f32x16 st0 = {}, st1 = {};                                             \
        __builtin_amdgcn_s_setprio(1);                                         \
        _Pragma("unroll")                                                      \
        for (int s = 0; s < 4; ++s) {                                          \
            const int r0 = lo5, r1 = 32 + lo5;                                 \
            bf16x8 kf0 = *(const bf16x8*)&Kc[r0 * 64 + (((s * 2 + hi) ^ SWZ3(r0)) << 3)]; \
            bf16x8 kf1 = *(const bf16x8*)&Kc[r1 * 64 + (((s * 2 + hi) ^ SWZ3(r1)) << 3)]; \
            st0 = __builtin_amdgcn_mfma_f32_32x32x16_bf16(kf0, qf[s], st0, 0, 0, 0); \
            st1 = __builtin_amdgcn_mfma_f32_32x32x16_bf16(kf1, qf[s], st1, 0, 0, 0); \
        }                                                                      \
        __builtin_amdgcn_s_setprio(0);                                         \
        /* in-register softmax numerator */                                    \
        float p[32];                                                           \
        float a0 = 0.f, a1 = 0.f, a2 = 0.f, a3 = 0.f;                          \
        _Pragma("unroll")                                                      \
        for (int r = 0; r < 16; ++r) {                                         \
            float s0 = fminf(st0[r] * SC, 50.f);                               \
            float s1 = fminf(st1[r] * SC, 50.f);                               \
            p[r]      = __builtin_amdgcn_exp2f(s0);                            \
            p[16 + r] = __builtin_amdgcn_exp2f(s1);                            \
            if (r & 1) { a1 += p[r]; a3 += p[16 + r]; }                        \
            else       { a0 += p[r]; a2 += p[16 + r]; }                        \
        }                                                                      \
        ls0 += a0 + a1; ls1 += a2 + a3;                                        \
        /* pack P^T B-frags: 16 cvt_pk + 8 permlane32_swap */                  \
        union { u32 wd[4]; bf16x8 v; } fr[4];                                  \
        _Pragma("unroll")                                                      \
        for (int ks = 0; ks < 4; ++ks) {                                       \
            const int b = (ks & 1) * 8 + (ks >> 1) * 16;                       \
            u32 A0 = cvtpk(p[b + 0], p[b + 1]);                                \
            u32 C0 = cvtpk(p[b + 2], p[b + 3]);                                \
            u32 B0 = cvtpk(p[b + 4], p[b + 5]);                                \
            u32 D0 = cvtpk(p[b + 6], p[b + 7]);                                \
            pswap(A0, B0);                                                     \
            pswap(C0, D0);                                                     \
            fr[ks].wd[0] = A0; fr[ks].wd[1] = C0;                              \
            fr[ks].wd[2] = B0; fr[ks].wd[3] = D0;                              \
        }                                                                      \
        /* PV: O^T += V^T * P^T */                                             \
        const bf16* Vc = Vt[CUR];                                              \
        __builtin_amdgcn_s_setprio(1);                                         \
        _Pragma("unroll")                                                      \
        for (int ks = 0; ks < 4; ++ks) {                                       \
            const int r0 = lo5, r1 = 32 + lo5;                                 \
            bf16x8 vf0 = *(const bf16x8*)&Vc[r0 * 64 + (((ks * 2 + hi) ^ SWZ3(r0)) << 3)]; \
            bf16x8 vf1 = *(const bf16x8*)&Vc[r1 * 64 + (((ks * 2 + hi) ^ SWZ3(r1)) << 3)]; \
            acc0 = __builtin_amdgcn_mfma_f32_32x32x16_bf16(vf0, fr[ks].v, acc0, 0, 0, 0); \
            acc1 = __builtin_amdgcn_mfma_f32_32x32x16_bf16(vf1, fr[ks].v, acc1, 0, 0, 0); \
        }                                                                      \
        __builtin_amdgcn_s_setprio(0);                                         \
        /* drain next-chunk loads, write V^T, single barrier */                \
        asm volatile("s_waitcnt vmcnt(0)" ::: "memory");                       \
        {                                                                      \
            bf16x8 v0, v1;                                                     \
            _Pragma("unroll")                                                  \
            for (int i = 0; i < 8; ++i) { v0[i] = u[i][0]; v1[i] = u[i][1]; }  \
            bf16* Vn = Vt[(CUR) ^ 1];                                          \
            *(bf16x8*)&Vn[(vd + 0) * 64 + (((tid & 7) ^ SWZ3(vd + 0)) << 3)] = v0; \
            *(bf16x8*)&Vn[(vd + 1) * 64 + (((tid & 7) ^ SWZ3(vd + 1)) << 3)] = v1; \
        }                                                                      \
        __syncthreads();                                                       \
    }

    for (int c = 0; c < SEQ; c += 128) {
        BODY(0, c + 64)
        BODY(1, c + 128)
    }
#undef BODY

    // total row sum: other half of keys lives in lane^32
    float lt = ls0 + ls1;
    lt += __shfl_xor(lt, 32);
    const float inv = 1.0f / lt;

    // O^T -> O: lane writes row q = q0+w*32+lo5, d = dt*32 + g*8 + 4*hi + i
    bf16* orow = O + (size_t)(q0 + w * 32 + lo5) * DMODEL + h * 64;
    #pragma unroll
    for (int g = 0; g < 4; ++g) {
        bf16x4 o4;
        o4[0] = (bf16)(acc0[g * 4 + 0] * inv);
        o4[1] = (bf16)(acc0[g * 4 + 1] * inv);
        o4[2] = (bf16)(acc0[g * 4 + 2] * inv);
        o4[3] = (bf16)(acc0[g * 4 + 3] * inv);
        *(bf16x4*)&orow[g * 8 + 4 * hi] = o4;
        bf16x4 o5;
        o5[0] = (bf16)(acc1[g * 4 + 0] * inv);
        o5[1] = (bf16)(acc1[g * 4 + 1] * inv);
        o5[2] = (bf16)(acc1[g * 4 + 2] * inv);
        o5[3] = (bf16)(acc1[g * 4 + 3] * inv);
        *(bf16x4*)&orow[32 + g * 8 + 4 * hi] = o5;
    }
}

// ---------------------------------------------------------------------------
extern "C" void kernel_launch(void* const* d_in, const int* in_sizes, int n_in,
                              void* d_out, int out_size, void* d_ws, size_t ws_size,
                              hipStream_t stream)
{
    const float* q   = (const float*)d_in[0];
    const float* k   = (const float*)d_in[1];
    const float* v   = (const float*)d_in[2];
    const float* Wq  = (const float*)d_in[3];
    const float* Wk  = (const float*)d_in[4];
    const float* Wv  = (const float*)d_in[5];
    const float* Wfc = (const float*)d_in[6];
    float* out = (float*)d_out;

    const int EM = SEQ * DMODEL;
    const int WM = DMODEL * DMODEL;

    bf16* qb   = (bf16*)d_ws;
    bf16* kb   = qb + EM;
    bf16* vb   = kb + EM;
    bf16* Wqb  = vb + EM;
    bf16* Wkb  = Wqb + WM;
    bf16* Wvb  = Wkb + WM;
    bf16* Wfcb = Wvb + WM;
    bf16* Pq   = Wfcb + WM;
    bf16* Pk   = Pq + EM;
    bf16* Pv   = Pk + EM;
    bf16* AO   = Pv + EM;

    cvt_bf16<<<EM / 2048, 256, 0, stream>>>(q,   qb,   EM);
    cvt_bf16<<<EM / 2048, 256, 0, stream>>>(k,   kb,   EM);
    cvt_bf16<<<EM / 2048, 256, 0, stream>>>(v,   vb,   EM);
    cvt_bf16<<<WM / 2048, 256, 0, stream>>>(Wq,  Wqb,  WM);
    cvt_bf16<<<WM / 2048, 256, 0, stream>>>(Wk,  Wkb,  WM);
    cvt_bf16<<<WM / 2048, 256, 0, stream>>>(Wv,  Wvb,  WM);
    cvt_bf16<<<WM / 2048, 256, 0, stream>>>(Wfc, Wfcb, WM);

    dim3 gg(DMODEL / 128, SEQ / 64);
    gemm_mfma<0><<<gg, 256, 0, stream>>>(qb, Wqb, Pq, nullptr, nullptr, SEQ, DMODEL, DMODEL);
    gemm_mfma<0><<<gg, 256, 0, stream>>>(kb, Wkb, Pk, nullptr, nullptr, SEQ, DMODEL, DMODEL);
    gemm_mfma<0><<<gg, 256, 0, stream>>>(vb, Wvb, Pv, nullptr, nullptr, SEQ, DMODEL, DMODEL);

    attn_mfma<<<512, 256, 0, stream>>>(Pq, Pk, Pv, AO);

    gemm_mfma<1><<<gg, 256, 0, stream>>>(AO, Wfcb, nullptr, out, q, SEQ, DMODEL, DMODEL);
}